// Round 4
// baseline (216.587 us; speedup 1.0000x reference)
//
#include <hip/hip_runtime.h>

#define NK 19
#define NB 8
#define NC 256
#define NP 8192           // 64*128
#define NBP (NB*NP)       // 65536

typedef unsigned char u8;

// ---------------- kernel 1: argmax over classes + integer counts ----------------
__global__ __launch_bounds__(256) void k_argmax(const float* __restrict__ target,
                                                u8* __restrict__ lab,
                                                int* __restrict__ counts) {
  __shared__ float tl[256 * NK];                 // 19456 B
  __shared__ int lcnt[NK];
  if (threadIdx.x < NK) lcnt[threadIdx.x] = 0;
  const float4* src = (const float4*)(target + (size_t)blockIdx.x * (256 * NK));
  float4* dst = (float4*)tl;
  for (int i = threadIdx.x; i < 256 * NK / 4; i += 256) dst[i] = src[i];
  __syncthreads();
  const float* row = &tl[threadIdx.x * NK];
  float best = row[0]; int bk = 0;
#pragma unroll
  for (int k = 1; k < NK; ++k) { float v = row[k]; if (v > best) { best = v; bk = k; } }
  int g = blockIdx.x * 256 + threadIdx.x;
  lab[g] = (u8)bk;
  atomicAdd(&lcnt[bk], 1);
  __syncthreads();
  int b = g >> 13;                               // / NP (block is within one b)
  if (threadIdx.x < NK) atomicAdd(&counts[b * NK + threadIdx.x], lcnt[threadIdx.x]);
}

// ---------------- kernel 2: per-(feat,b,c) class sums via wave-private ds_add_f32 ----------------
// bins[wave][k][lane]: each address touched by exactly ONE lane of ONE wave, in
// program order -> bit-deterministic. ds_add_f32 is fire-and-forget: no RMW chain.
__global__ __launch_bounds__(256) void k_sums(const float* __restrict__ fS,
                                              const float* __restrict__ fT,
                                              const u8* __restrict__ lab,
                                              float* __restrict__ sums) {
  __shared__ float bins[4 * NK * 64];            // 19456 B; bank = lane%32, conflict-free
  int id = blockIdx.x;                           // [0, 2*NB*NC)
  int f = id >> 11;
  int b = (id >> 8) & 7;
  int c = id & 255;
  int t = threadIdx.x, wave = t >> 6, lane = t & 63;
  // zero (stride-1 float4, conflict-free)
  float4* bz = (float4*)bins;
  for (int i = t; i < NK * 64; i += 256) bz[i] = make_float4(0.f, 0.f, 0.f, 0.f);
  __syncthreads();
  const float4* rv = (const float4*)((f ? fT : fS) + ((size_t)(b * NC + c)) * NP);
  const uchar4* lb = (const uchar4*)(lab + b * NP);
  // prefetch everything: 8 float4 + 8 uchar4 in flight, one wait
  float4 v[8]; uchar4 l[8];
#pragma unroll
  for (int i = 0; i < 8; ++i) { v[i] = rv[i * 256 + t]; l[i] = lb[i * 256 + t]; }
  float* bw = &bins[wave * (NK * 64) + lane];
#pragma unroll
  for (int i = 0; i < 8; ++i) {
    atomicAdd(bw + (int)l[i].x * 64, v[i].x);    // ds_add_f32, no return
    atomicAdd(bw + (int)l[i].y * 64, v[i].y);
    atomicAdd(bw + (int)l[i].z * 64, v[i].z);
    atomicAdd(bw + (int)l[i].w * 64, v[i].w);
  }
  __syncthreads();
  // reduce: wave w handles classes w, w+4, ...; fixed-order, deterministic
  for (int k = wave; k < NK; k += 4) {
    float a0 = bins[0 * (NK * 64) + k * 64 + lane];
    float a1 = bins[1 * (NK * 64) + k * 64 + lane];
    float a2 = bins[2 * (NK * 64) + k * 64 + lane];
    float a3 = bins[3 * (NK * 64) + k * 64 + lane];
    float s = (a0 + a1) + (a2 + a3);
#pragma unroll
    for (int off = 32; off > 0; off >>= 1) s += __shfl_down(s, off, 64);
    if (lane == 0) sums[(size_t)id * NK + k] = s;
  }
}

// ---------------- kernel 3: means + per-(f,b,k) center norms ----------------
__global__ __launch_bounds__(256) void k_means(const float* __restrict__ sums,
                                               const int* __restrict__ counts,
                                               float* __restrict__ means,
                                               float* __restrict__ cnorm) {
  int b = blockIdx.x / NK, k = blockIdx.x % NK;
  int c = threadIdx.x;
  float cnt = (float)counts[b * NK + k] + 1e-6f;
  size_t iS = ((size_t)(b * NC + c)) * NK + k;
  size_t iT = ((size_t)((NB + b) * NC + c)) * NK + k;
  float mS = sums[iS] / cnt;
  float mT = sums[iT] / cnt;
  means[iS] = mS;
  means[iT] = mT;
  float sS = mS * mS, sT = mT * mT;
#pragma unroll
  for (int off = 32; off > 0; off >>= 1) { sS += __shfl_down(sS, off, 64); sT += __shfl_down(sT, off, 64); }
  __shared__ float redS[4], redT[4];
  int wid = threadIdx.x >> 6, lane = threadIdx.x & 63;
  if (lane == 0) { redS[wid] = sS; redT[wid] = sT; }
  __syncthreads();
  if (threadIdx.x == 0) {
    float tS = redS[0] + redS[1] + redS[2] + redS[3];
    float tT = redT[0] + redT[1] + redT[2] + redT[3];
    cnorm[b * NK + k]           = fmaxf(sqrtf(tS), 1e-8f);
    cnorm[NB * NK + b * NK + k] = fmaxf(sqrtf(tT), 1e-8f);
  }
}

// ---------------- kernel 4: per-pixel cosine + squared diff (4-way channel split) ----------------
__global__ __launch_bounds__(256) void k_cos(const float* __restrict__ fS,
                                             const float* __restrict__ fT,
                                             const u8* __restrict__ lab,
                                             const float* __restrict__ means,
                                             const float* __restrict__ cnorm,
                                             float* __restrict__ partial) {
  __shared__ float R[1024];                      // 4 KB
  int b = blockIdx.x >> 7, pt = blockIdx.x & 127;
  int t = threadIdx.x;
  int px = t & 63, cg = t >> 6;                  // 4 channel-groups x 64 pixels
  int p = pt * 64 + px;
  int k = lab[b * NP + p];
  const float* rs = fS + (size_t)b * NC * NP + p;
  const float* rt = fT + (size_t)b * NC * NP + p;
  const float* mSb = means + (size_t)(b * NC) * NK;
  const float* mTb = means + (size_t)((NB + b) * NC) * NK;
  float dS = 0.f, nS = 0.f, dT = 0.f, nT = 0.f;
  int c0 = cg * 64;
#pragma unroll 8
  for (int j = 0; j < 64; ++j) {
    int c = c0 + j;
    float vS = rs[(size_t)c * NP];
    float vT = rt[(size_t)c * NP];
    float cS = mSb[c * NK + k];
    float cT = mTb[c * NK + k];
    dS += vS * cS; nS += vS * vS;
    dT += vT * cT; nT += vT * vT;
  }
  R[t] = dS; R[256 + t] = nS; R[512 + t] = dT; R[768 + t] = nT;
  __syncthreads();
  if (t < 64) {
    dS = R[t]       + R[64 + t]  + R[128 + t] + R[192 + t];
    nS = R[256 + t] + R[320 + t] + R[384 + t] + R[448 + t];
    dT = R[512 + t] + R[576 + t] + R[640 + t] + R[704 + t];
    nT = R[768 + t] + R[832 + t] + R[896 + t] + R[960 + t];
    float cnS = cnorm[b * NK + k];
    float cnT = cnorm[NB * NK + b * NK + k];
    float cosS = dS / (fmaxf(sqrtf(nS), 1e-8f) * cnS);
    float cosT = dT / (fmaxf(sqrtf(nT), 1e-8f) * cnT);
    float d = cosS - cosT;
    float v = d * d;
#pragma unroll
    for (int off = 32; off > 0; off >>= 1) v += __shfl_down(v, off, 64);
    if (px == 0) partial[blockIdx.x] = v;
  }
}

// ---------------- kernel 5: final deterministic reduction (1024 partials) ----------------
__global__ __launch_bounds__(256) void k_final(const float* __restrict__ partial,
                                               float* __restrict__ out) {
  int t = threadIdx.x;
  float v = partial[t] + partial[256 + t] + partial[512 + t] + partial[768 + t];
#pragma unroll
  for (int off = 32; off > 0; off >>= 1) v += __shfl_down(v, off, 64);
  __shared__ float red[4];
  int wid = t >> 6, lane = t & 63;
  if (lane == 0) red[wid] = v;
  __syncthreads();
  if (t == 0) out[0] = (red[0] + red[1] + red[2] + red[3]) * (1.0f / (float)NBP);
}

// ---------------- launch ----------------
extern "C" void kernel_launch(void* const* d_in, const int* in_sizes, int n_in,
                              void* d_out, int out_size, void* d_ws, size_t ws_size,
                              hipStream_t stream) {
  const float* fS     = (const float*)d_in[0];
  const float* fT     = (const float*)d_in[1];
  const float* target = (const float*)d_in[2];
  char* ws = (char*)d_ws;
  u8*    lab     = (u8*)   (ws + 0);        // 65536 B
  int*   counts  = (int*)  (ws + 65536);    // 608 B (pad to 66560)
  float* sums    = (float*)(ws + 66560);    // 311296 B -> 377856
  float* means   = (float*)(ws + 377856);   // 311296 B -> 689152
  float* cnorm   = (float*)(ws + 689152);   // 1216 B (pad to 690432)
  float* partial = (float*)(ws + 690432);   // 4096 B
  float* out = (float*)d_out;

  hipMemsetAsync(counts, 0, NB * NK * sizeof(int), stream);
  k_argmax<<<NBP / 256,   256, 0, stream>>>(target, lab, counts);
  k_sums  <<<2 * NB * NC, 256, 0, stream>>>(fS, fT, lab, sums);
  k_means <<<NB * NK,     256, 0, stream>>>(sums, counts, means, cnorm);
  k_cos   <<<NB * (NP / 64), 256, 0, stream>>>(fS, fT, lab, means, cnorm, partial);
  k_final <<<1, 256, 0, stream>>>(partial, out);
}

// Round 5
// 74.057 us; speedup vs baseline: 2.9246x; 2.9246x over previous
//
#include <hip/hip_runtime.h>

#define NK 19
#define NB 8
#define NC 256
#define NP 8192           // 64*128
#define NBP (NB*NP)       // 65536

typedef unsigned char u8;

// ---------------- kernel 1: argmax over classes + integer counts ----------------
__global__ __launch_bounds__(256) void k_argmax(const float* __restrict__ target,
                                                u8* __restrict__ lab,
                                                int* __restrict__ counts) {
  __shared__ float tl[256 * NK];                 // 19456 B
  __shared__ int lcnt[NK];
  if (threadIdx.x < NK) lcnt[threadIdx.x] = 0;
  const float4* src = (const float4*)(target + (size_t)blockIdx.x * (256 * NK));
  float4* dst = (float4*)tl;
  for (int i = threadIdx.x; i < 256 * NK / 4; i += 256) dst[i] = src[i];
  __syncthreads();
  const float* row = &tl[threadIdx.x * NK];
  float best = row[0]; int bk = 0;
#pragma unroll
  for (int k = 1; k < NK; ++k) { float v = row[k]; if (v > best) { best = v; bk = k; } }
  int g = blockIdx.x * 256 + threadIdx.x;
  lab[g] = (u8)bk;
  atomicAdd(&lcnt[bk], 1);
  __syncthreads();
  int b = g >> 13;                               // / NP (block is within one b)
  if (threadIdx.x < NK) atomicAdd(&counts[b * NK + threadIdx.x], lcnt[threadIdx.x]);
}

// ---------------- kernel 2: per-(feat,b,c) class sums, bin-major hist ----------------
// bins[l*256+t]: bank = t%32 independent of label -> zero conflicts (verified R3).
// All 16 global loads issued BEFORE sched_barrier(0) so the compiler cannot
// re-roll them into the RMW chain (R3/R4 showed VGPR=16 => serialized loads).
__global__ __launch_bounds__(256) void k_sums(const float* __restrict__ fS,
                                              const float* __restrict__ fT,
                                              const u8* __restrict__ lab,
                                              float* __restrict__ sums) {
  __shared__ float bins[NK * 256];               // 19456 B
  int id = blockIdx.x;                           // [0, 2*NB*NC)
  int f = id >> 11;
  int b = (id >> 8) & 7;
  int c = id & 255;
  int t = threadIdx.x;
  const float4* rv = (const float4*)((f ? fT : fS) + ((size_t)(b * NC + c)) * NP);
  const uchar4* lb = (const uchar4*)(lab + b * NP);
  // ---- issue ALL loads (8 float4 + 8 uchar4 in flight) ----
  float4 v0 = rv[0 * 256 + t], v1 = rv[1 * 256 + t], v2 = rv[2 * 256 + t], v3 = rv[3 * 256 + t];
  float4 v4 = rv[4 * 256 + t], v5 = rv[5 * 256 + t], v6 = rv[6 * 256 + t], v7 = rv[7 * 256 + t];
  uchar4 l0 = lb[0 * 256 + t], l1 = lb[1 * 256 + t], l2 = lb[2 * 256 + t], l3 = lb[3 * 256 + t];
  uchar4 l4 = lb[4 * 256 + t], l5 = lb[5 * 256 + t], l6 = lb[6 * 256 + t], l7 = lb[7 * 256 + t];
  __builtin_amdgcn_sched_barrier(0);             // pin loads above; uses below
  // ---- zero histogram while loads are in flight ----
  float4* bz = (float4*)bins;
  for (int i = t; i < NK * 64; i += 256) bz[i] = make_float4(0.f, 0.f, 0.f, 0.f);
  __syncthreads();
  // ---- accumulate (serial per-thread RMW chain, DS-pipe bound across 32 waves) ----
#define ACC(L, V) \
  bins[(int)L.x * 256 + t] += V.x; \
  bins[(int)L.y * 256 + t] += V.y; \
  bins[(int)L.z * 256 + t] += V.z; \
  bins[(int)L.w * 256 + t] += V.w;
  ACC(l0, v0) ACC(l1, v1) ACC(l2, v2) ACC(l3, v3)
  ACC(l4, v4) ACC(l5, v5) ACC(l6, v6) ACC(l7, v7)
#undef ACC
  __syncthreads();
  // ---- reduce: wave w handles classes w, w+4, ...; deterministic ----
  int wave = t >> 6, lane = t & 63;
  for (int k = wave; k < NK; k += 4) {
    float4 v = *(const float4*)&bins[k * 256 + lane * 4];
#pragma unroll
    for (int off = 32; off > 0; off >>= 1) {
      v.x += __shfl_down(v.x, off);
      v.y += __shfl_down(v.y, off);
      v.z += __shfl_down(v.z, off);
      v.w += __shfl_down(v.w, off);
    }
    if (lane == 0) sums[(size_t)id * NK + k] = (v.x + v.y) + (v.z + v.w);
  }
}

// ---------------- kernel 3: means + per-(f,b,k) center norms ----------------
__global__ __launch_bounds__(256) void k_means(const float* __restrict__ sums,
                                               const int* __restrict__ counts,
                                               float* __restrict__ means,
                                               float* __restrict__ cnorm) {
  int b = blockIdx.x / NK, k = blockIdx.x % NK;
  int c = threadIdx.x;
  float cnt = (float)counts[b * NK + k] + 1e-6f;
  size_t iS = ((size_t)(b * NC + c)) * NK + k;
  size_t iT = ((size_t)((NB + b) * NC + c)) * NK + k;
  float mS = sums[iS] / cnt;
  float mT = sums[iT] / cnt;
  means[iS] = mS;
  means[iT] = mT;
  float sS = mS * mS, sT = mT * mT;
#pragma unroll
  for (int off = 32; off > 0; off >>= 1) { sS += __shfl_down(sS, off, 64); sT += __shfl_down(sT, off, 64); }
  __shared__ float redS[4], redT[4];
  int wid = threadIdx.x >> 6, lane = threadIdx.x & 63;
  if (lane == 0) { redS[wid] = sS; redT[wid] = sT; }
  __syncthreads();
  if (threadIdx.x == 0) {
    float tS = redS[0] + redS[1] + redS[2] + redS[3];
    float tT = redT[0] + redT[1] + redT[2] + redT[3];
    cnorm[b * NK + k]           = fmaxf(sqrtf(tS), 1e-8f);
    cnorm[NB * NK + b * NK + k] = fmaxf(sqrtf(tT), 1e-8f);
  }
}

// ---------------- kernel 4: per-pixel cosine + squared diff (4-way channel split) ----------------
__global__ __launch_bounds__(256) void k_cos(const float* __restrict__ fS,
                                             const float* __restrict__ fT,
                                             const u8* __restrict__ lab,
                                             const float* __restrict__ means,
                                             const float* __restrict__ cnorm,
                                             float* __restrict__ partial) {
  __shared__ float R[1024];                      // 4 KB
  int b = blockIdx.x >> 7, pt = blockIdx.x & 127;
  int t = threadIdx.x;
  int px = t & 63, cg = t >> 6;                  // 4 channel-groups x 64 pixels
  int p = pt * 64 + px;
  int k = lab[b * NP + p];
  const float* rs = fS + (size_t)b * NC * NP + p;
  const float* rt = fT + (size_t)b * NC * NP + p;
  const float* mSb = means + (size_t)(b * NC) * NK;
  const float* mTb = means + (size_t)((NB + b) * NC) * NK;
  float dS = 0.f, nS = 0.f, dT = 0.f, nT = 0.f;
  int c0 = cg * 64;
#pragma unroll 8
  for (int j = 0; j < 64; ++j) {
    int c = c0 + j;
    float vS = rs[(size_t)c * NP];
    float vT = rt[(size_t)c * NP];
    float cS = mSb[c * NK + k];
    float cT = mTb[c * NK + k];
    dS += vS * cS; nS += vS * vS;
    dT += vT * cT; nT += vT * vT;
  }
  R[t] = dS; R[256 + t] = nS; R[512 + t] = dT; R[768 + t] = nT;
  __syncthreads();
  if (t < 64) {
    dS = R[t]       + R[64 + t]  + R[128 + t] + R[192 + t];
    nS = R[256 + t] + R[320 + t] + R[384 + t] + R[448 + t];
    dT = R[512 + t] + R[576 + t] + R[640 + t] + R[704 + t];
    nT = R[768 + t] + R[832 + t] + R[896 + t] + R[960 + t];
    float cnS = cnorm[b * NK + k];
    float cnT = cnorm[NB * NK + b * NK + k];
    float cosS = dS / (fmaxf(sqrtf(nS), 1e-8f) * cnS);
    float cosT = dT / (fmaxf(sqrtf(nT), 1e-8f) * cnT);
    float d = cosS - cosT;
    float v = d * d;
#pragma unroll
    for (int off = 32; off > 0; off >>= 1) v += __shfl_down(v, off, 64);
    if (px == 0) partial[blockIdx.x] = v;
  }
}

// ---------------- kernel 5: final deterministic reduction (1024 partials) ----------------
__global__ __launch_bounds__(256) void k_final(const float* __restrict__ partial,
                                               float* __restrict__ out) {
  int t = threadIdx.x;
  float v = partial[t] + partial[256 + t] + partial[512 + t] + partial[768 + t];
#pragma unroll
  for (int off = 32; off > 0; off >>= 1) v += __shfl_down(v, off, 64);
  __shared__ float red[4];
  int wid = t >> 6, lane = t & 63;
  if (lane == 0) red[wid] = v;
  __syncthreads();
  if (t == 0) out[0] = (red[0] + red[1] + red[2] + red[3]) * (1.0f / (float)NBP);
}

// ---------------- launch ----------------
extern "C" void kernel_launch(void* const* d_in, const int* in_sizes, int n_in,
                              void* d_out, int out_size, void* d_ws, size_t ws_size,
                              hipStream_t stream) {
  const float* fS     = (const float*)d_in[0];
  const float* fT     = (const float*)d_in[1];
  const float* target = (const float*)d_in[2];
  char* ws = (char*)d_ws;
  u8*    lab     = (u8*)   (ws + 0);        // 65536 B
  int*   counts  = (int*)  (ws + 65536);    // 608 B (pad to 66560)
  float* sums    = (float*)(ws + 66560);    // 311296 B -> 377856
  float* means   = (float*)(ws + 377856);   // 311296 B -> 689152
  float* cnorm   = (float*)(ws + 689152);   // 1216 B (pad to 690432)
  float* partial = (float*)(ws + 690432);   // 4096 B
  float* out = (float*)d_out;

  hipMemsetAsync(counts, 0, NB * NK * sizeof(int), stream);
  k_argmax<<<NBP / 256,   256, 0, stream>>>(target, lab, counts);
  k_sums  <<<2 * NB * NC, 256, 0, stream>>>(fS, fT, lab, sums);
  k_means <<<NB * NK,     256, 0, stream>>>(sums, counts, means, cnorm);
  k_cos   <<<NB * (NP / 64), 256, 0, stream>>>(fS, fT, lab, means, cnorm, partial);
  k_final <<<1, 256, 0, stream>>>(partial, out);
}

// Round 6
// 65.331 us; speedup vs baseline: 3.3152x; 1.1336x over previous
//
#include <hip/hip_runtime.h>

#define NK 19
#define NB 8
#define NC 256
#define NP 8192           // 64*128
#define NBP (NB*NP)       // 65536

typedef unsigned char u8;

// ---------------- kernel 1: argmax over classes + integer counts ----------------
__global__ __launch_bounds__(256) void k_argmax(const float* __restrict__ target,
                                                u8* __restrict__ lab,
                                                int* __restrict__ counts) {
  __shared__ float tl[256 * NK];                 // 19456 B
  __shared__ int lcnt[NK];
  if (threadIdx.x < NK) lcnt[threadIdx.x] = 0;
  const float4* src = (const float4*)(target + (size_t)blockIdx.x * (256 * NK));
  float4* dst = (float4*)tl;
  for (int i = threadIdx.x; i < 256 * NK / 4; i += 256) dst[i] = src[i];
  __syncthreads();
  const float* row = &tl[threadIdx.x * NK];
  float best = row[0]; int bk = 0;
#pragma unroll
  for (int k = 1; k < NK; ++k) { float v = row[k]; if (v > best) { best = v; bk = k; } }
  int g = blockIdx.x * 256 + threadIdx.x;
  lab[g] = (u8)bk;
  atomicAdd(&lcnt[bk], 1);
  __syncthreads();
  int b = g >> 13;                               // / NP (block is within one b)
  if (threadIdx.x < NK) atomicAdd(&counts[b * NK + threadIdx.x], lcnt[threadIdx.x]);
}

// ---------------- kernel 2: class sums, 2 channels/block, tree-fold reduce ----------------
// bins[ch][l][t]: bank = t%32, label-independent -> conflict-free RMW (verified R3).
// Reduce via LDS float4 tree fold (~1.3K cy/block) instead of __shfl (DS-pipe ~4K cy).
__global__ __launch_bounds__(256) void k_sums(const float* __restrict__ fS,
                                              const float* __restrict__ fT,
                                              const u8* __restrict__ lab,
                                              float* __restrict__ sums) {
  __shared__ float bins[2 * NK * 256];           // 38912 B
  int id = blockIdx.x;                           // [0, 2048)
  int f = id >> 10;
  int b = (id >> 7) & 7;
  int c0 = (id & 127) * 2;
  int t = threadIdx.x;
  const float* base = (f ? fT : fS) + ((size_t)(b * NC + c0)) * NP;
  const float4* rvA = (const float4*)base;        // channel c0
  const float4* rvB = (const float4*)(base + NP); // channel c0+1
  const uchar4* lb  = (const uchar4*)(lab + b * NP);
  uchar4 l[8]; float4 vA[8], vB[8];
#pragma unroll
  for (int i = 0; i < 8; ++i) l[i] = lb[i * 256 + t];
#pragma unroll
  for (int i = 0; i < 8; ++i) { vA[i] = rvA[i * 256 + t]; vB[i] = rvB[i * 256 + t]; }
  // zero histogram (2432 float4s)
  float4* bz = (float4*)bins;
#pragma unroll
  for (int i = 0; i < 10; ++i) {
    int idx = i * 256 + t;
    if (idx < 2 * NK * 64) bz[idx] = make_float4(0.f, 0.f, 0.f, 0.f);
  }
  __syncthreads();
  // accumulate: two independent RMW chains (ch A and ch B), conflict-free banks
#pragma unroll
  for (int i = 0; i < 8; ++i) {
    bins[(int)l[i].x * 256 + t] += vA[i].x;
    bins[(int)l[i].y * 256 + t] += vA[i].y;
    bins[(int)l[i].z * 256 + t] += vA[i].z;
    bins[(int)l[i].w * 256 + t] += vA[i].w;
    bins[2 * NK * 256 / 2 + (int)l[i].x * 256 + t] += vB[i].x;   // +4864
    bins[2 * NK * 256 / 2 + (int)l[i].y * 256 + t] += vB[i].y;
    bins[2 * NK * 256 / 2 + (int)l[i].z * 256 + t] += vB[i].z;
    bins[2 * NK * 256 / 2 + (int)l[i].w * 256 + t] += vB[i].w;
  }
  __syncthreads();
  // tree fold: 38 rows (ch*19+k), each 64 float4; fold 32/16/8/4 then finish
  float4* F = (float4*)bins;
  for (int j = t; j < 38 * 32; j += 256) { int r = j >> 5, i = j & 31; F[r * 64 + i] += F[r * 64 + i + 32]; }
  __syncthreads();
  for (int j = t; j < 38 * 16; j += 256) { int r = j >> 4, i = j & 15; F[r * 64 + i] += F[r * 64 + i + 16]; }
  __syncthreads();
  for (int j = t; j < 38 * 8;  j += 256) { int r = j >> 3, i = j & 7;  F[r * 64 + i] += F[r * 64 + i + 8];  }
  __syncthreads();
  for (int j = t; j < 38 * 4;  j += 256) { int r = j >> 2, i = j & 3;  F[r * 64 + i] += F[r * 64 + i + 4];  }
  __syncthreads();
  if (t < 38) {
    float4 a = F[t * 64 + 0], b4 = F[t * 64 + 1], c4 = F[t * 64 + 2], d4 = F[t * 64 + 3];
    float s = (((a.x + a.y) + (a.z + a.w)) + ((b4.x + b4.y) + (b4.z + b4.w)))
            + (((c4.x + c4.y) + (c4.z + c4.w)) + ((d4.x + d4.y) + (d4.z + d4.w)));
    int ch = t / NK, k = t - ch * NK;
    sums[((size_t)((f * NB + b) * NC + c0 + ch)) * NK + k] = s;
  }
}

// ---------------- kernel 3: means + per-(f,b,k) center norms ----------------
__global__ __launch_bounds__(256) void k_means(const float* __restrict__ sums,
                                               const int* __restrict__ counts,
                                               float* __restrict__ means,
                                               float* __restrict__ cnorm) {
  int b = blockIdx.x / NK, k = blockIdx.x % NK;
  int c = threadIdx.x;
  float cnt = (float)counts[b * NK + k] + 1e-6f;
  size_t iS = ((size_t)(b * NC + c)) * NK + k;
  size_t iT = ((size_t)((NB + b) * NC + c)) * NK + k;
  float mS = sums[iS] / cnt;
  float mT = sums[iT] / cnt;
  means[iS] = mS;
  means[iT] = mT;
  float sS = mS * mS, sT = mT * mT;
#pragma unroll
  for (int off = 32; off > 0; off >>= 1) { sS += __shfl_down(sS, off, 64); sT += __shfl_down(sT, off, 64); }
  __shared__ float redS[4], redT[4];
  int wid = threadIdx.x >> 6, lane = threadIdx.x & 63;
  if (lane == 0) { redS[wid] = sS; redT[wid] = sT; }
  __syncthreads();
  if (threadIdx.x == 0) {
    float tS = redS[0] + redS[1] + redS[2] + redS[3];
    float tT = redT[0] + redT[1] + redT[2] + redT[3];
    cnorm[b * NK + k]           = fmaxf(sqrtf(tS), 1e-8f);
    cnorm[NB * NK + b * NK + k] = fmaxf(sqrtf(tT), 1e-8f);
  }
}

// ---------------- kernel 4: per-pixel cosine + squared diff (4-way channel split) ----------------
__global__ __launch_bounds__(256) void k_cos(const float* __restrict__ fS,
                                             const float* __restrict__ fT,
                                             const u8* __restrict__ lab,
                                             const float* __restrict__ means,
                                             const float* __restrict__ cnorm,
                                             float* __restrict__ partial) {
  __shared__ float R[1024];                      // 4 KB
  int b = blockIdx.x >> 7, pt = blockIdx.x & 127;
  int t = threadIdx.x;
  int px = t & 63, cg = t >> 6;                  // 4 channel-groups x 64 pixels
  int p = pt * 64 + px;
  int k = lab[b * NP + p];
  const float* rs = fS + (size_t)b * NC * NP + p;
  const float* rt = fT + (size_t)b * NC * NP + p;
  const float* mSb = means + (size_t)(b * NC) * NK;
  const float* mTb = means + (size_t)((NB + b) * NC) * NK;
  float dS = 0.f, nS = 0.f, dT = 0.f, nT = 0.f;
  int c0 = cg * 64;
#pragma unroll 8
  for (int j = 0; j < 64; ++j) {
    int c = c0 + j;
    float vS = rs[(size_t)c * NP];
    float vT = rt[(size_t)c * NP];
    float cS = mSb[c * NK + k];
    float cT = mTb[c * NK + k];
    dS += vS * cS; nS += vS * vS;
    dT += vT * cT; nT += vT * vT;
  }
  R[t] = dS; R[256 + t] = nS; R[512 + t] = dT; R[768 + t] = nT;
  __syncthreads();
  if (t < 64) {
    dS = R[t]       + R[64 + t]  + R[128 + t] + R[192 + t];
    nS = R[256 + t] + R[320 + t] + R[384 + t] + R[448 + t];
    dT = R[512 + t] + R[576 + t] + R[640 + t] + R[704 + t];
    nT = R[768 + t] + R[832 + t] + R[896 + t] + R[960 + t];
    float cnS = cnorm[b * NK + k];
    float cnT = cnorm[NB * NK + b * NK + k];
    float cosS = dS / (fmaxf(sqrtf(nS), 1e-8f) * cnS);
    float cosT = dT / (fmaxf(sqrtf(nT), 1e-8f) * cnT);
    float d = cosS - cosT;
    float v = d * d;
#pragma unroll
    for (int off = 32; off > 0; off >>= 1) v += __shfl_down(v, off, 64);
    if (px == 0) partial[blockIdx.x] = v;
  }
}

// ---------------- kernel 5: final deterministic reduction (1024 partials) ----------------
__global__ __launch_bounds__(256) void k_final(const float* __restrict__ partial,
                                               float* __restrict__ out) {
  int t = threadIdx.x;
  float v = partial[t] + partial[256 + t] + partial[512 + t] + partial[768 + t];
#pragma unroll
  for (int off = 32; off > 0; off >>= 1) v += __shfl_down(v, off, 64);
  __shared__ float red[4];
  int wid = t >> 6, lane = t & 63;
  if (lane == 0) red[wid] = v;
  __syncthreads();
  if (t == 0) out[0] = (red[0] + red[1] + red[2] + red[3]) * (1.0f / (float)NBP);
}

// ---------------- launch ----------------
extern "C" void kernel_launch(void* const* d_in, const int* in_sizes, int n_in,
                              void* d_out, int out_size, void* d_ws, size_t ws_size,
                              hipStream_t stream) {
  const float* fS     = (const float*)d_in[0];
  const float* fT     = (const float*)d_in[1];
  const float* target = (const float*)d_in[2];
  char* ws = (char*)d_ws;
  u8*    lab     = (u8*)   (ws + 0);        // 65536 B
  int*   counts  = (int*)  (ws + 65536);    // 608 B (pad to 66560)
  float* sums    = (float*)(ws + 66560);    // 311296 B -> 377856
  float* means   = (float*)(ws + 377856);   // 311296 B -> 689152
  float* cnorm   = (float*)(ws + 689152);   // 1216 B (pad to 690432)
  float* partial = (float*)(ws + 690432);   // 4096 B
  float* out = (float*)d_out;

  hipMemsetAsync(counts, 0, NB * NK * sizeof(int), stream);
  k_argmax<<<NBP / 256,   256, 0, stream>>>(target, lab, counts);
  k_sums  <<<2 * NB * 128, 256, 0, stream>>>(fS, fT, lab, sums);
  k_means <<<NB * NK,     256, 0, stream>>>(sums, counts, means, cnorm);
  k_cos   <<<NB * (NP / 64), 256, 0, stream>>>(fS, fT, lab, means, cnorm, partial);
  k_final <<<1, 256, 0, stream>>>(partial, out);
}